// Round 6
// baseline (283.815 us; speedup 1.0000x reference)
//
#include <hip/hip_runtime.h>
#include <cstdint>
#include <cstddef>

#define BN_EPS 1e-5f
#define BATCH 8192

typedef unsigned long long u64;
typedef uint32_t u32;
typedef int v4i __attribute__((ext_vector_type(4)));
typedef int v16i __attribute__((ext_vector_type(16)));

// float <-> total-order key (ascending with float order on finites)
__device__ __forceinline__ u32 f2k(float f) {
    u32 u = __float_as_uint(f);
    return (u >> 31) ? ~u : (u | 0x80000000u);
}
__device__ __forceinline__ float k2f(u32 k) {
    u32 u = (k & 0x80000000u) ? (k ^ 0x80000000u) : ~k;
    return __uint_as_float(u);
}
// exact fp32 BN chain — bit-identical to the reference epilogue semantics
__device__ __forceinline__ float bn_eval(float conv, float B, float iv, float sh) {
    return __fadd_rn(__fmul_rn(__fadd_rn(conv, B), iv), sh);
}

// ---------------- one merged prep kernel ----------------
__global__ __launch_bounds__(256) void prep_all(
    const float* w1, const float* b1, const float* w2, const float* b2,
    const float* w3, const float* b3, const float* w4, const float* b4,
    const float* wf,
    const float* g1, const float* be1, const float* m1, const float* v1,
    const float* g2, const float* be2, const float* m2, const float* v2,
    const float* g3, const float* be3, const float* m3, const float* v3,
    const float* g4, const float* be4, const float* m4, const float* v4,
    float* s1f, float* T1, u32* wt2w, int* T2,
    uint4* b3i8, int* C3, u64* wt4, int* T4, u64* wtf) {
    int t = blockIdx.x * 256 + threadIdx.x;

    if (t < 384) {
        // layer1 sign weights, slope-folded, float4-padded: s1f[co*12 + k], k<9
        int co = t / 12, k = t % 12;
        float val = 0.f;
        if (k < 9) {
            float iv = g1[co] * rsqrtf(v1[co] + BN_EPS);
            float d = (iv < 0.f) ? -1.f : 1.f;
            val = ((w1[co * 9 + k] >= 0.f) ? 1.f : -1.f) * d;
        }
        s1f[t] = val;
    } else if (t < 416) {
        // layer1 fp threshold via total-order bisection: bit = (sum' >= T1[co])
        int co = t - 384;
        float iv = g1[co] * rsqrtf(v1[co] + BN_EPS);
        float sh = be1[co] - m1[co] * iv;
        float B = b1[co];
        bool flip = (iv < 0.f);
        auto pred = [&](float sp) {
            float sum = flip ? -sp : sp;
            return bn_eval(sum, B, iv, sh) >= 0.f;
        };
        u32 lo = f2k(-3.0e38f), hi = f2k(3.0e38f);
        float Tv;
        if (pred(k2f(lo))) Tv = k2f(lo);
        else if (!pred(k2f(hi))) Tv = __uint_as_float(0x7F800000u);
        else {
            while (hi - lo > 1u) {
                u32 mid = lo + ((hi - lo) >> 1);
                if (pred(k2f(mid))) hi = mid; else lo = mid;
            }
            Tv = k2f(hi);
        }
        T1[co] = Tv;
    } else if (t < 608) {
        // layer2 packed (complemented if iv<0) weights: [co][kw] u32x4 rows
        int idx = t - 416;
        int co = idx / 3, kw = idx % 3;
        float iv = g2[co] * rsqrtf(v2[co] + BN_EPS);
        bool flip = (iv < 0.f);
        u32 wb = 0;
        for (int ci = 0; ci < 32; ++ci)
            wb |= (u32)((w2[(co * 32 + ci) * 3 + kw] >= 0.f) != flip) << ci;
        wt2w[co * 4 + kw] = wb;
    } else if (t < 800) {
        // layer2 thresholds: cls 0=interior, 1=left edge, 2=right edge
        int idx = t - 608;
        int co = idx & 63, cls = idx >> 6;
        float iv = g2[co] * rsqrtf(v2[co] + BN_EPS);
        float sh = be2[co] - m2[co] * iv;
        float B = b2[co];
        bool flip = (iv < 0.f);
        int spur = 0, nv = 3;
        if (cls == 1) { nv = 2; for (int ci = 0; ci < 32; ++ci) spur += (int)((w2[(co * 32 + ci) * 3 + 0] >= 0.f) != flip); }
        if (cls == 2) { nv = 2; for (int ci = 0; ci < 32; ++ci) spur += (int)((w2[(co * 32 + ci) * 3 + 2] >= 0.f) != flip); }
        int maxp = 32 * nv + spur;
        int T = -1;
        for (int p = 0; p <= maxp; ++p) {
            int conv = flip ? (2 * (p - spur) - 32 * nv) : (32 * nv - 2 * (p - spur));
            float y = bn_eval((float)conv, B, iv, sh);
            if ((y >= 0.f) && (T == p - 1)) T = p;
        }
        T2[cls * 64 + co] = T;
    } else if (t < 2336) {
        // layer3 B as i8 (+-1, sign-folded by sign(iv)): [q][n][16 bytes]
        int idx = t - 800;
        int q = idx >> 7, n = idx & 127;
        float iv = g3[n] * rsqrtf(v3[n] + BN_EPS);
        bool flip = (iv < 0.f);
        int kw = q >> 2, ci0 = (q & 3) * 16;
        u32 wd[4] = {0, 0, 0, 0};
        for (int j = 0; j < 16; ++j) {
            int ci = ci0 + j;
            bool pos = (w3[(n * 64 + ci) * 3 + kw] >= 0.f) != flip;
            u32 byte = pos ? 0x01u : 0xFFu;
            wd[j >> 2] |= byte << (8 * (j & 3));
        }
        b3i8[idx] = make_uint4(wd[0], wd[1], wd[2], wd[3]);
    } else if (t < 2464) {
        // layer3 integer conv-threshold: bit <=> conv' >= C3[co]
        int co = t - 2336;
        float iv = g3[co] * rsqrtf(v3[co] + BN_EPS);
        float sh = be3[co] - m3[co] * iv;
        float B = b3[co];
        int C = 1000;
        if (iv >= 0.f) {
            for (int v = -192; v <= 192; v += 2)
                if (bn_eval((float)v, B, iv, sh) >= 0.f) { C = v; break; }
        } else {
            for (int v = 192; v >= -192; v -= 2)
                if (bn_eval((float)v, B, iv, sh) >= 0.f) { C = -v; break; }
        }
        C3[co] = C;
    } else if (t < 4000) {
        // layer4 packed weights
        int idx = t - 2464;
        int j = idx & 1, ch = idx >> 1;
        int co = ch / 6, h = ch % 6;
        float iv = g4[co] * rsqrtf(v4[co] + BN_EPS);
        bool flip = (iv < 0.f);
        u64 wb = 0;
        for (int cb = 0; cb < 64; ++cb) {
            int ci = j * 64 + cb;
            wb |= (u64)((w4[(co * 128 + ci) * 6 + h] >= 0.f) != flip) << cb;
        }
        wt4[idx] = wb;
    } else if (t < 4128) {
        // layer4 thresholds
        int co = t - 4000;
        float iv = g4[co] * rsqrtf(v4[co] + BN_EPS);
        float sh = be4[co] - m4[co] * iv;
        float B = b4[co];
        bool flip = (iv < 0.f);
        int T = -1;
        for (int p = 0; p <= 768; ++p) {
            int conv = flip ? (2 * p - 768) : (768 - 2 * p);
            float y = bn_eval((float)conv, B, iv, sh);
            if ((y >= 0.f) && (T == p - 1)) T = p;
        }
        T4[co] = T;
    } else if (t < 4448) {
        // fc weights
        int idx = t - 4128;
        int o = idx / 32, wi = idx % 32;
        u64 wb = 0;
        for (int fb = 0; fb < 64; ++fb)
            wb |= (u64)(wf[o * 2048 + wi * 64 + fb] >= 0.f) << fb;
        wtf[idx] = wb;
    }
}

// ---------------- fused layer1+layer2 ----------------
// Block = 8 (b,h) rows x 32 w positions. Phase A: fp32 conv + threshold sign
// + pool-OR -> a1 word in LDS. Phase B: xnor conv 32ci->64co from LDS.
#define L12_ROWS 8
__global__ __launch_bounds__(256) void layer12_kernel(
    const float* __restrict__ x, const float4* __restrict__ s1p, const float* __restrict__ T1,
    const uint4* __restrict__ wt2v, const int* __restrict__ T2, u64* __restrict__ a2) {
    __shared__ float4 sS[96];            // [co*3+j]: k0-3, k4-7, {k8,0,0,0}
    __shared__ float sT[32];
    __shared__ uint4 sW[64];
    __shared__ int sT2[192];
    __shared__ u32 sA1[L12_ROWS][32];
    int t = threadIdx.x;
    if (t < 96) sS[t] = s1p[t];
    if (t < 32) sT[t] = T1[t];
    if (t < 64) sW[t] = wt2v[t];
    if (t < 192) sT2[t] = T2[t];
    __syncthreads();

    int r = t >> 5, wp = t & 31;
    int bh = blockIdx.x * L12_ROWS + r;
    const float* xp = x + (size_t)bh * 128;
    float xv[11];
    int p0 = 4 * wp - 4;
#pragma unroll
    for (int j = 0; j < 11; ++j) {
        int p = p0 + j;
        xv[j] = (p >= 0 && p < 128) ? xp[p] : 0.f;
    }
    u32 word = 0;
#pragma unroll
    for (int co = 0; co < 32; ++co) {
        float4 wa = sS[co * 3 + 0];
        float4 wb = sS[co * 3 + 1];
        float wc = sS[co * 3 + 2].x;
        // identical accumulation order to previous verified kernel: k=0..8 fmaf chain
        float sum0 = 0.f, sum1 = 0.f;
        sum0 = fmaf(wa.x, xv[0], sum0);  sum1 = fmaf(wa.x, xv[2], sum1);
        sum0 = fmaf(wa.y, xv[1], sum0);  sum1 = fmaf(wa.y, xv[3], sum1);
        sum0 = fmaf(wa.z, xv[2], sum0);  sum1 = fmaf(wa.z, xv[4], sum1);
        sum0 = fmaf(wa.w, xv[3], sum0);  sum1 = fmaf(wa.w, xv[5], sum1);
        sum0 = fmaf(wb.x, xv[4], sum0);  sum1 = fmaf(wb.x, xv[6], sum1);
        sum0 = fmaf(wb.y, xv[5], sum0);  sum1 = fmaf(wb.y, xv[7], sum1);
        sum0 = fmaf(wb.z, xv[6], sum0);  sum1 = fmaf(wb.z, xv[8], sum1);
        sum0 = fmaf(wb.w, xv[7], sum0);  sum1 = fmaf(wb.w, xv[9], sum1);
        sum0 = fmaf(wc,   xv[8], sum0);  sum1 = fmaf(wc,   xv[10], sum1);
        float Tt = sT[co];
        word |= (u32)((sum0 >= Tt) || (sum1 >= Tt)) << co;
    }
    sA1[r][wp] = word;
    __syncthreads();

    u32 am = sA1[r][wp];
    u32 al = (wp > 0) ? sA1[r][wp - 1] : 0u;
    u32 ar = (wp < 31) ? sA1[r][wp + 1] : 0u;
    const int* Tp = &sT2[(wp == 0) ? 64 : ((wp == 31) ? 128 : 0)];
    u64 word2 = 0;
#pragma unroll
    for (int co = 0; co < 64; ++co) {
        uint4 wv = sW[co];
        int p = __popc(al ^ wv.x) + __popc(am ^ wv.y) + __popc(ar ^ wv.z);
        word2 |= (u64)(p <= Tp[co]) << co;
    }
    a2[(size_t)bh * 32 + wp] = word2;
}

// ---------------- layer 3: i8 MFMA conv (1x3, p1) 64ci->128co + pool-OR ----------------
// One wave per (b,h) row: M=32 positions, N=128 co, K=192 (3 taps x 64 ci).
#define L3_ROWS 4
__global__ __launch_bounds__(256) void layer3_mfma(
    const u64* __restrict__ a2, const uint4* __restrict__ b3i8, const int* __restrict__ C3,
    u32* __restrict__ a3u32) {
    __shared__ uint4 sB[12 * 128];    // [q*128 + n][16 i8]  (24576 B)
    __shared__ u64 sLUT[256];         // byte -> 8 bytes of +1/-1
    __shared__ int sC3[128];
    int t = threadIdx.x;
    for (int i = t; i < 1536; i += 256) sB[i] = b3i8[i];
    {
        u32 b = t & 255;
        u64 e = 0;
#pragma unroll
        for (int j = 0; j < 8; ++j)
            e |= (((b >> j) & 1) ? 0x01ull : 0xFFull) << (8 * j);
        if (t < 256) sLUT[t] = e;
    }
    if (t < 128) sC3[t] = C3[t];
    __syncthreads();

    int wv = t >> 6, lane = t & 63, m = lane & 31, half = lane >> 5;
    int rowBase = (blockIdx.x * 4 + wv) * L3_ROWS;
    const int prTab[8] = {0, 1, 4, 5, 8, 9, 12, 13};

    for (int r = 0; r < L3_ROWS; ++r) {
        int bh = rowBase + r;
        u64 aw = a2[(size_t)bh * 32 + m];
        u64 wm1 = __shfl(aw, m - 1);
        u64 wp1 = __shfl(aw, m + 1);

        v4i A[6];
#pragma unroll
        for (int kk = 0; kk < 6; ++kk) {
            const int kw = kk >> 1;
            u64 word = (kw == 0) ? wm1 : ((kw == 1) ? aw : wp1);
            bool valid = !((kw == 0 && m == 0) || (kw == 2 && m == 31));
            int ci0 = ((kk & 1) << 5) + (half << 4);
            u32 bits = (u32)(word >> ci0) & 0xFFFFu;
            u64 lo = sLUT[bits & 0xFF];
            u64 hi = sLUT[bits >> 8];
            if (!valid) { lo = 0; hi = 0; }
            union { u64 q[2]; v4i v; } u;
            u.q[0] = lo; u.q[1] = hi;
            A[kk] = u.v;
        }

        u32 outv = 0;
#pragma unroll
        for (int nt = 0; nt < 4; ++nt) {
            v16i acc;
#pragma unroll
            for (int i = 0; i < 16; ++i) acc[i] = 0;
#pragma unroll
            for (int kk = 0; kk < 6; ++kk) {
                int q = kk * 2 + half;
                union { uint4 u4; v4i v; } bu;
                bu.u4 = sB[q * 128 + nt * 32 + m];
                acc = __builtin_amdgcn_mfma_i32_32x32x32_i8(A[kk], bu.v, acc, 0, 0, 0);
            }
            int tc = sC3[nt * 32 + m];
#pragma unroll
            for (int rp = 0; rp < 8; ++rp) {
                bool c = (acc[2 * rp] >= tc) || (acc[2 * rp + 1] >= tc);
                u64 mk = __ballot(c);
                int LA = (nt << 4) | prTab[rp];
                int LB = LA + 2;
                outv = (lane == LA) ? (u32)mk : outv;
                outv = (lane == LB) ? (u32)(mk >> 32) : outv;
            }
        }
        a3u32[(size_t)bh * 64 + ((lane & 15) << 2) + (lane >> 4)] = outv;
    }
}

// ---------------- layer 4 (6x1 conv) + FC (2048->10) ----------------
__global__ __launch_bounds__(256) void layer4_fc_kernel(
    const u64* __restrict__ a3, const u64* __restrict__ wt4, const int* __restrict__ T4,
    const u64* __restrict__ wtf, const float* __restrict__ bf, float* __restrict__ out) {
    __shared__ u64 sW4[1536];
    __shared__ u64 sWf[320];
    __shared__ u64 sFeat[16][32];
    __shared__ int sT[128];
    __shared__ float sBf[10];
    int t = threadIdx.x;
    {
        ulonglong2* d = (ulonglong2*)sW4;
        const ulonglong2* s = (const ulonglong2*)wt4;
        for (int i = t; i < 768; i += 256) d[i] = s[i];
        ulonglong2* df = (ulonglong2*)sWf;
        const ulonglong2* sf = (const ulonglong2*)wtf;
        if (t < 160) df[t] = sf[t];
    }
    if (t < 128) sT[t] = T4[t];
    if (t < 10) sBf[t] = bf[t];
    __syncthreads();
    int bb = t >> 4, w = t & 15, lane = t & 63, g = lane >> 4;
    int b = blockIdx.x * 16 + bb;
    u64 av[12];
#pragma unroll
    for (int h = 0; h < 6; ++h) {
        av[h * 2 + 0] = a3[(size_t)b * 192 + h * 32 + w * 2 + 0];
        av[h * 2 + 1] = a3[(size_t)b * 192 + h * 32 + w * 2 + 1];
    }
    u64 acc = 0;
#pragma unroll 8
    for (int co = 0; co < 128; ++co) {
        const u64* wr = &sW4[co * 12];
        int p = 0;
#pragma unroll
        for (int q = 0; q < 12; ++q) p += __popcll(av[q] ^ wr[q]);
        u64 m = __ballot(p <= sT[co]);
        u64 field = (m >> (g * 16)) & 0xFFFFull;
        acc |= field << ((co & 3) << 4);
        if ((co & 3) == 3) {
            if (w == 0) sFeat[bb][co >> 2] = acc;
            acc = 0;
        }
    }
    __syncthreads();
    if (t < 160) {
        int fb = t / 10, o = t % 10;
        int p = 0;
#pragma unroll
        for (int wi = 0; wi < 32; ++wi) p += __popcll(sFeat[fb][wi] ^ sWf[o * 32 + wi]);
        out[(size_t)(blockIdx.x * 16 + fb) * 10 + o] = __fadd_rn((float)(2048 - 2 * p), sBf[o]);
    }
}

// ---------------- launch ----------------
extern "C" void kernel_launch(void* const* d_in, const int* in_sizes, int n_in,
                              void* d_out, int out_size, void* d_ws, size_t ws_size,
                              hipStream_t stream) {
    const float* x  = (const float*)d_in[0];
    const float* w1 = (const float*)d_in[1];  const float* b1 = (const float*)d_in[2];
    const float* w2 = (const float*)d_in[3];  const float* b2 = (const float*)d_in[4];
    const float* w3 = (const float*)d_in[5];  const float* b3 = (const float*)d_in[6];
    const float* w4 = (const float*)d_in[7];  const float* b4 = (const float*)d_in[8];
    const float* g1 = (const float*)d_in[9];  const float* be1 = (const float*)d_in[10];
    const float* m1 = (const float*)d_in[11]; const float* v1 = (const float*)d_in[12];
    const float* g2 = (const float*)d_in[13]; const float* be2 = (const float*)d_in[14];
    const float* m2 = (const float*)d_in[15]; const float* v2 = (const float*)d_in[16];
    const float* g3 = (const float*)d_in[17]; const float* be3 = (const float*)d_in[18];
    const float* m3 = (const float*)d_in[19]; const float* v3 = (const float*)d_in[20];
    const float* g4 = (const float*)d_in[21]; const float* be4 = (const float*)d_in[22];
    const float* m4 = (const float*)d_in[23]; const float* v4 = (const float*)d_in[24];
    const float* wf = (const float*)d_in[25]; const float* bf = (const float*)d_in[26];
    float* out = (float*)d_out;

    char* ws = (char*)d_ws;
    u64* a2 = (u64*)(ws + 0);                 // 8192*6*32 u64  = 12582912 B
    u64* a3 = (u64*)(ws + 12582912);          // 8192*6*16*2 u64 = 12582912 B
    const size_t S = 25165824;
    uint4* b3i8 = (uint4*)(ws + S + 0);       // 24576 B
    u64*  wt4  = (u64*) (ws + S + 24576);     // 12288 B
    u64*  wtf  = (u64*) (ws + S + 36864);     // 2560 B
    u32*  wt2w = (u32*) (ws + S + 39424);     // 1024 B
    float* s1f = (float*)(ws + S + 40448);    // 384 floats (96 float4) 1536 B
    float* T1  = (float*)(ws + S + 41984);    // 128 B
    int*  T2   = (int*)  (ws + S + 42112);    // 768 B
    int*  C3   = (int*)  (ws + S + 42880);    // 512 B
    int*  T4   = (int*)  (ws + S + 43392);    // 512 B

    prep_all<<<18, 256, 0, stream>>>(w1, b1, w2, b2, w3, b3, w4, b4, wf,
                                     g1, be1, m1, v1, g2, be2, m2, v2,
                                     g3, be3, m3, v3, g4, be4, m4, v4,
                                     s1f, T1, wt2w, T2, b3i8, C3, wt4, T4, wtf);

    layer12_kernel<<<(BATCH * 6) / L12_ROWS, 256, 0, stream>>>(
        x, (const float4*)s1f, T1, (const uint4*)wt2w, T2, a2);
    layer3_mfma<<<(BATCH * 6) / (4 * L3_ROWS), 256, 0, stream>>>(a2, b3i8, C3, (u32*)a3);
    layer4_fc_kernel<<<BATCH / 16, 256, 0, stream>>>(a3, wt4, T4, wtf, bf, out);
}

// Round 7
// 280.860 us; speedup vs baseline: 1.0105x; 1.0105x over previous
//
#include <hip/hip_runtime.h>
#include <cstdint>
#include <cstddef>

#define BN_EPS 1e-5f
#define BATCH 8192

typedef unsigned long long u64;
typedef uint32_t u32;
typedef int v4i __attribute__((ext_vector_type(4)));
typedef int v16i __attribute__((ext_vector_type(16)));

// float <-> total-order key (ascending with float order on finites)
__device__ __forceinline__ u32 f2k(float f) {
    u32 u = __float_as_uint(f);
    return (u >> 31) ? ~u : (u | 0x80000000u);
}
__device__ __forceinline__ float k2f(u32 k) {
    u32 u = (k & 0x80000000u) ? (k ^ 0x80000000u) : ~k;
    return __uint_as_float(u);
}
// exact fp32 BN chain — bit-identical to the reference epilogue semantics
__device__ __forceinline__ float bn_eval(float conv, float B, float iv, float sh) {
    return __fadd_rn(__fmul_rn(__fadd_rn(conv, B), iv), sh);
}

// ---------------- one merged prep kernel ----------------
__global__ __launch_bounds__(256) void prep_all(
    const float* w1, const float* b1, const float* w2, const float* b2,
    const float* w3, const float* b3, const float* w4, const float* b4,
    const float* wf,
    const float* g1, const float* be1, const float* m1, const float* v1,
    const float* g2, const float* be2, const float* m2, const float* v2,
    const float* g3, const float* be3, const float* m3, const float* v3,
    const float* g4, const float* be4, const float* m4, const float* v4,
    float* s1f, float* T1, u32* wt2w, int* T2,
    uint4* b3i8, int* C3, u64* wt4, int* T4, u64* wtf) {
    int t = blockIdx.x * 256 + threadIdx.x;

    if (t < 384) {
        // layer1 sign weights, slope-folded, float4-padded: s1f[co*12 + k], k<9
        int co = t / 12, k = t % 12;
        float val = 0.f;
        if (k < 9) {
            float iv = g1[co] * rsqrtf(v1[co] + BN_EPS);
            float d = (iv < 0.f) ? -1.f : 1.f;
            val = ((w1[co * 9 + k] >= 0.f) ? 1.f : -1.f) * d;
        }
        s1f[t] = val;
    } else if (t < 416) {
        // layer1 fp threshold via total-order bisection: bit = (sum' >= T1[co])
        int co = t - 384;
        float iv = g1[co] * rsqrtf(v1[co] + BN_EPS);
        float sh = be1[co] - m1[co] * iv;
        float B = b1[co];
        bool flip = (iv < 0.f);
        auto pred = [&](float sp) {
            float sum = flip ? -sp : sp;
            return bn_eval(sum, B, iv, sh) >= 0.f;
        };
        u32 lo = f2k(-3.0e38f), hi = f2k(3.0e38f);
        float Tv;
        if (pred(k2f(lo))) Tv = k2f(lo);
        else if (!pred(k2f(hi))) Tv = __uint_as_float(0x7F800000u);
        else {
            while (hi - lo > 1u) {
                u32 mid = lo + ((hi - lo) >> 1);
                if (pred(k2f(mid))) hi = mid; else lo = mid;
            }
            Tv = k2f(hi);
        }
        T1[co] = Tv;
    } else if (t < 608) {
        // layer2 packed (complemented if iv<0) weights: [co][kw] u32x4 rows
        int idx = t - 416;
        int co = idx / 3, kw = idx % 3;
        float iv = g2[co] * rsqrtf(v2[co] + BN_EPS);
        bool flip = (iv < 0.f);
        u32 wb = 0;
        for (int ci = 0; ci < 32; ++ci)
            wb |= (u32)((w2[(co * 32 + ci) * 3 + kw] >= 0.f) != flip) << ci;
        wt2w[co * 4 + kw] = wb;
    } else if (t < 800) {
        // layer2 thresholds: cls 0=interior, 1=left edge, 2=right edge
        int idx = t - 608;
        int co = idx & 63, cls = idx >> 6;
        float iv = g2[co] * rsqrtf(v2[co] + BN_EPS);
        float sh = be2[co] - m2[co] * iv;
        float B = b2[co];
        bool flip = (iv < 0.f);
        int spur = 0, nv = 3;
        if (cls == 1) { nv = 2; for (int ci = 0; ci < 32; ++ci) spur += (int)((w2[(co * 32 + ci) * 3 + 0] >= 0.f) != flip); }
        if (cls == 2) { nv = 2; for (int ci = 0; ci < 32; ++ci) spur += (int)((w2[(co * 32 + ci) * 3 + 2] >= 0.f) != flip); }
        int maxp = 32 * nv + spur;
        int T = -1;
        for (int p = 0; p <= maxp; ++p) {
            int conv = flip ? (2 * (p - spur) - 32 * nv) : (32 * nv - 2 * (p - spur));
            float y = bn_eval((float)conv, B, iv, sh);
            if ((y >= 0.f) && (T == p - 1)) T = p;
        }
        T2[cls * 64 + co] = T;
    } else if (t < 2336) {
        // layer3 B as i8 (+-1, sign-folded by sign(iv)): [q][n][16 bytes]
        int idx = t - 800;
        int q = idx >> 7, n = idx & 127;
        float iv = g3[n] * rsqrtf(v3[n] + BN_EPS);
        bool flip = (iv < 0.f);
        int kw = q >> 2, ci0 = (q & 3) * 16;
        u32 wd[4] = {0, 0, 0, 0};
        for (int j = 0; j < 16; ++j) {
            int ci = ci0 + j;
            bool pos = (w3[(n * 64 + ci) * 3 + kw] >= 0.f) != flip;
            u32 byte = pos ? 0x01u : 0xFFu;
            wd[j >> 2] |= byte << (8 * (j & 3));
        }
        b3i8[idx] = make_uint4(wd[0], wd[1], wd[2], wd[3]);
    } else if (t < 2464) {
        // layer3 integer conv-threshold: bit <=> conv' >= C3[co]
        int co = t - 2336;
        float iv = g3[co] * rsqrtf(v3[co] + BN_EPS);
        float sh = be3[co] - m3[co] * iv;
        float B = b3[co];
        int C = 1000;
        if (iv >= 0.f) {
            for (int v = -192; v <= 192; v += 2)
                if (bn_eval((float)v, B, iv, sh) >= 0.f) { C = v; break; }
        } else {
            for (int v = 192; v >= -192; v -= 2)
                if (bn_eval((float)v, B, iv, sh) >= 0.f) { C = -v; break; }
        }
        C3[co] = C;
    } else if (t < 4000) {
        // layer4 packed weights
        int idx = t - 2464;
        int j = idx & 1, ch = idx >> 1;
        int co = ch / 6, h = ch % 6;
        float iv = g4[co] * rsqrtf(v4[co] + BN_EPS);
        bool flip = (iv < 0.f);
        u64 wb = 0;
        for (int cb = 0; cb < 64; ++cb) {
            int ci = j * 64 + cb;
            wb |= (u64)((w4[(co * 128 + ci) * 6 + h] >= 0.f) != flip) << cb;
        }
        wt4[idx] = wb;
    } else if (t < 4128) {
        // layer4 thresholds
        int co = t - 4000;
        float iv = g4[co] * rsqrtf(v4[co] + BN_EPS);
        float sh = be4[co] - m4[co] * iv;
        float B = b4[co];
        bool flip = (iv < 0.f);
        int T = -1;
        for (int p = 0; p <= 768; ++p) {
            int conv = flip ? (2 * p - 768) : (768 - 2 * p);
            float y = bn_eval((float)conv, B, iv, sh);
            if ((y >= 0.f) && (T == p - 1)) T = p;
        }
        T4[co] = T;
    } else if (t < 4448) {
        // fc weights
        int idx = t - 4128;
        int o = idx / 32, wi = idx % 32;
        u64 wb = 0;
        for (int fb = 0; fb < 64; ++fb)
            wb |= (u64)(wf[o * 2048 + wi * 64 + fb] >= 0.f) << fb;
        wtf[idx] = wb;
    }
}

// ---------------- fused layer1+layer2, v2 ----------------
// Phase A: thread = (co = t&31, row rr = t>>5). Weights in VGPRs; x row in LDS
// with 4-float zero pads; sliding 12-float window (1 ds_read_b128/position).
// Sign bits assembled via ballot (lane=co; one ballot covers 2 rows).
// Phase B: thread = (row, wp), 64-co xnor-popcount from LDS a1 words.
#define L12_ROWS 8
__global__ __launch_bounds__(256) void layer12_kernel(
    const float* __restrict__ x, const float4* __restrict__ s1p, const float* __restrict__ T1,
    const uint4* __restrict__ wt2v, const int* __restrict__ T2, u64* __restrict__ a2) {
    __shared__ float sX[L12_ROWS][144];   // [row][4 zeros | 128 x | 12 zeros]
    __shared__ u32 sA1[L12_ROWS][32];
    __shared__ uint4 sW[64];
    __shared__ int sT2[192];
    int t = threadIdx.x;
    int bh0 = blockIdx.x * L12_ROWS;
    for (int i = t; i < L12_ROWS * 144; i += 256) {
        int r = i / 144, c = i % 144;
        float v = 0.f;
        if (c >= 4 && c < 132) v = x[(size_t)(bh0 + r) * 128 + (c - 4)];
        sX[r][c] = v;
    }
    if (t < 64) sW[t] = wt2v[t];
    if (t < 192) sT2[t] = T2[t];

    int co = t & 31, rr = t >> 5, lane = t & 63;
    float4 wa = s1p[co * 3 + 0];
    float4 wb = s1p[co * 3 + 1];
    float wc = s1p[co * 3 + 2].x;
    float Tt = T1[co];
    __syncthreads();

    const float* xr = sX[rr];
    float4 A0 = *(const float4*)&xr[0];
    float4 A1 = *(const float4*)&xr[4];
    float4 A2 = *(const float4*)&xr[8];
    u32 myword = 0;
    for (int wp = 0; wp < 32; ++wp) {
        // xv[j] = sX[rr][4wp + j]; identical fmaf order to previous verified kernel
        float sum0 = 0.f, sum1 = 0.f;
        sum0 = fmaf(wa.x, A0.x, sum0);  sum1 = fmaf(wa.x, A0.z, sum1);
        sum0 = fmaf(wa.y, A0.y, sum0);  sum1 = fmaf(wa.y, A0.w, sum1);
        sum0 = fmaf(wa.z, A0.z, sum0);  sum1 = fmaf(wa.z, A1.x, sum1);
        sum0 = fmaf(wa.w, A0.w, sum0);  sum1 = fmaf(wa.w, A1.y, sum1);
        sum0 = fmaf(wb.x, A1.x, sum0);  sum1 = fmaf(wb.x, A1.z, sum1);
        sum0 = fmaf(wb.y, A1.y, sum0);  sum1 = fmaf(wb.y, A1.w, sum1);
        sum0 = fmaf(wb.z, A1.z, sum0);  sum1 = fmaf(wb.z, A2.x, sum1);
        sum0 = fmaf(wb.w, A1.w, sum0);  sum1 = fmaf(wb.w, A2.y, sum1);
        sum0 = fmaf(wc,   A2.x, sum0);  sum1 = fmaf(wc,   A2.z, sum1);
        bool pred = (sum0 >= Tt) || (sum1 >= Tt);
        u64 mk = __ballot(pred);
        u32 hw = (lane < 32) ? (u32)mk : (u32)(mk >> 32);
        if ((lane & 31) == wp) myword = hw;
        A0 = A1; A1 = A2;
        A2 = *(const float4*)&xr[4 * wp + 12];   // wp=31 reads pad [136..139], in-bounds
    }
    // lane L of wave W holds word for row 2W + (L>=32), wp = L&31
    sA1[((t >> 6) << 1) + (lane >> 5)][lane & 31] = myword;
    __syncthreads();

    int r = t >> 5, wp = t & 31;
    u32 am = sA1[r][wp];
    u32 al = (wp > 0) ? sA1[r][wp - 1] : 0u;
    u32 ar = (wp < 31) ? sA1[r][wp + 1] : 0u;
    const int* Tp = &sT2[(wp == 0) ? 64 : ((wp == 31) ? 128 : 0)];
    u64 word2 = 0;
#pragma unroll
    for (int c = 0; c < 64; ++c) {
        uint4 wv = sW[c];
        int p = __popc(al ^ wv.x) + __popc(am ^ wv.y) + __popc(ar ^ wv.z);
        word2 |= (u64)(p <= Tp[c]) << c;
    }
    a2[(size_t)(bh0 + r) * 32 + wp] = word2;
}

// ---------------- fused layer3 (i8 MFMA + pool) + layer4 + FC ----------------
// Block = 16 batches = 96 (b,h) rows. 4 waves x 24 rows of MFMA; a3 in LDS
// (u64 row stride 33 to break bank conflicts); then L4+FC as verified before.
__global__ __launch_bounds__(256) void layer34_kernel(
    const u64* __restrict__ a2, const uint4* __restrict__ b3i8, const int* __restrict__ C3,
    const u64* __restrict__ wt4, const int* __restrict__ T4,
    const u64* __restrict__ wtf, const float* __restrict__ bf, float* __restrict__ out) {
    __shared__ uint4 sB[12 * 128];          // 24576 B
    __shared__ u64 sLUT[256];               // 2048 B
    __shared__ int sC3[128];                // 512 B
    __shared__ u64 sA3[96 * 33];            // 25344 B (stride 33 u64 per row)
    __shared__ u64 sW4[1536];               // 12288 B
    __shared__ u64 sWf[320];                // 2560 B
    __shared__ u64 sFeat[16][32];           // 4096 B
    __shared__ int sT[128];
    __shared__ float sBf[10];
    int t = threadIdx.x;
    for (int i = t; i < 1536; i += 256) sB[i] = b3i8[i];
    {
        u32 b = t & 255;
        u64 e = 0;
#pragma unroll
        for (int j = 0; j < 8; ++j)
            e |= (((b >> j) & 1) ? 0x01ull : 0xFFull) << (8 * j);
        if (t < 256) sLUT[t] = e;
    }
    if (t < 128) sC3[t] = C3[t];
    {
        ulonglong2* d = (ulonglong2*)sW4;
        const ulonglong2* s = (const ulonglong2*)wt4;
        for (int i = t; i < 768; i += 256) d[i] = s[i];
        ulonglong2* df = (ulonglong2*)sWf;
        const ulonglong2* sf = (const ulonglong2*)wtf;
        if (t < 160) df[t] = sf[t];
    }
    if (t < 128) sT[t] = T4[t];
    if (t < 10) sBf[t] = bf[t];
    __syncthreads();

    // ----- L3 phase -----
    int wv = t >> 6, lane = t & 63, m = lane & 31, half = lane >> 5;
    const int prTab[8] = {0, 1, 4, 5, 8, 9, 12, 13};
    u32* sA3u = (u32*)sA3;
    for (int r = 0; r < 24; ++r) {
        int rl = wv * 24 + r;
        int bh = blockIdx.x * 96 + rl;
        u64 aw = a2[(size_t)bh * 32 + m];
        u64 wm1 = __shfl(aw, m - 1);
        u64 wp1 = __shfl(aw, m + 1);

        v4i A[6];
#pragma unroll
        for (int kk = 0; kk < 6; ++kk) {
            const int kw = kk >> 1;
            u64 word = (kw == 0) ? wm1 : ((kw == 1) ? aw : wp1);
            bool valid = !((kw == 0 && m == 0) || (kw == 2 && m == 31));
            int ci0 = ((kk & 1) << 5) + (half << 4);
            u32 bits = (u32)(word >> ci0) & 0xFFFFu;
            u64 lo = sLUT[bits & 0xFF];
            u64 hi = sLUT[bits >> 8];
            if (!valid) { lo = 0; hi = 0; }
            union { u64 q[2]; v4i v; } u;
            u.q[0] = lo; u.q[1] = hi;
            A[kk] = u.v;
        }

        u32 outv = 0;
#pragma unroll
        for (int nt = 0; nt < 4; ++nt) {
            v16i acc;
#pragma unroll
            for (int i = 0; i < 16; ++i) acc[i] = 0;
#pragma unroll
            for (int kk = 0; kk < 6; ++kk) {
                int q = kk * 2 + half;
                union { uint4 u4; v4i v; } bu;
                bu.u4 = sB[q * 128 + nt * 32 + m];
                acc = __builtin_amdgcn_mfma_i32_32x32x32_i8(A[kk], bu.v, acc, 0, 0, 0);
            }
            int tc = sC3[nt * 32 + m];
#pragma unroll
            for (int rp = 0; rp < 8; ++rp) {
                bool c = (acc[2 * rp] >= tc) || (acc[2 * rp + 1] >= tc);
                u64 mk = __ballot(c);
                int LA = (nt << 4) | prTab[rp];
                int LB = LA + 2;
                outv = (lane == LA) ? (u32)mk : outv;
                outv = (lane == LB) ? (u32)(mk >> 32) : outv;
            }
        }
        // u32 index within row: pr*4 + nt  (pr = lane&15, nt = lane>>4)
        sA3u[rl * 66 + ((lane & 15) << 2) + (lane >> 4)] = outv;
    }
    __syncthreads();

    // ----- L4 + FC phase -----
    int bb = t >> 4, w = t & 15, g = lane >> 4;
    u64 av[12];
#pragma unroll
    for (int h = 0; h < 6; ++h) {
        av[h * 2 + 0] = sA3[(bb * 6 + h) * 33 + w * 2 + 0];
        av[h * 2 + 1] = sA3[(bb * 6 + h) * 33 + w * 2 + 1];
    }
    u64 acc = 0;
#pragma unroll 8
    for (int c = 0; c < 128; ++c) {
        const u64* wr = &sW4[c * 12];
        int p = 0;
#pragma unroll
        for (int q = 0; q < 12; ++q) p += __popcll(av[q] ^ wr[q]);
        u64 mk = __ballot(p <= sT[c]);
        u64 field = (mk >> (g * 16)) & 0xFFFFull;
        acc |= field << ((c & 3) << 4);
        if ((c & 3) == 3) {
            if (w == 0) sFeat[bb][c >> 2] = acc;
            acc = 0;
        }
    }
    __syncthreads();
    if (t < 160) {
        int fb = t / 10, o = t % 10;
        int p = 0;
#pragma unroll
        for (int wi = 0; wi < 32; ++wi) p += __popcll(sFeat[fb][wi] ^ sWf[o * 32 + wi]);
        out[(size_t)(blockIdx.x * 16 + fb) * 10 + o] = __fadd_rn((float)(2048 - 2 * p), sBf[o]);
    }
}

// ---------------- launch ----------------
extern "C" void kernel_launch(void* const* d_in, const int* in_sizes, int n_in,
                              void* d_out, int out_size, void* d_ws, size_t ws_size,
                              hipStream_t stream) {
    const float* x  = (const float*)d_in[0];
    const float* w1 = (const float*)d_in[1];  const float* b1 = (const float*)d_in[2];
    const float* w2 = (const float*)d_in[3];  const float* b2 = (const float*)d_in[4];
    const float* w3 = (const float*)d_in[5];  const float* b3 = (const float*)d_in[6];
    const float* w4 = (const float*)d_in[7];  const float* b4 = (const float*)d_in[8];
    const float* g1 = (const float*)d_in[9];  const float* be1 = (const float*)d_in[10];
    const float* m1 = (const float*)d_in[11]; const float* v1 = (const float*)d_in[12];
    const float* g2 = (const float*)d_in[13]; const float* be2 = (const float*)d_in[14];
    const float* m2 = (const float*)d_in[15]; const float* v2 = (const float*)d_in[16];
    const float* g3 = (const float*)d_in[17]; const float* be3 = (const float*)d_in[18];
    const float* m3 = (const float*)d_in[19]; const float* v3 = (const float*)d_in[20];
    const float* g4 = (const float*)d_in[21]; const float* be4 = (const float*)d_in[22];
    const float* m4 = (const float*)d_in[23]; const float* v4 = (const float*)d_in[24];
    const float* wf = (const float*)d_in[25]; const float* bf = (const float*)d_in[26];
    float* out = (float*)d_out;

    char* ws = (char*)d_ws;
    u64* a2 = (u64*)(ws + 0);                 // 8192*6*32 u64 = 12582912 B
    const size_t S = 12582912;
    uint4* b3i8 = (uint4*)(ws + S + 0);       // 24576 B
    u64*  wt4  = (u64*) (ws + S + 24576);     // 12288 B
    u64*  wtf  = (u64*) (ws + S + 36864);     // 2560 B
    u32*  wt2w = (u32*) (ws + S + 39424);     // 1024 B
    float* s1f = (float*)(ws + S + 40448);    // 1536 B
    float* T1  = (float*)(ws + S + 41984);    // 128 B
    int*  T2   = (int*)  (ws + S + 42112);    // 768 B
    int*  C3   = (int*)  (ws + S + 42880);    // 512 B
    int*  T4   = (int*)  (ws + S + 43392);    // 512 B

    prep_all<<<18, 256, 0, stream>>>(w1, b1, w2, b2, w3, b3, w4, b4, wf,
                                     g1, be1, m1, v1, g2, be2, m2, v2,
                                     g3, be3, m3, v3, g4, be4, m4, v4,
                                     s1f, T1, wt2w, T2, b3i8, C3, wt4, T4, wtf);

    layer12_kernel<<<(BATCH * 6) / L12_ROWS, 256, 0, stream>>>(
        x, (const float4*)s1f, T1, (const uint4*)wt2w, T2, a2);
    layer34_kernel<<<BATCH / 16, 256, 0, stream>>>(a2, b3i8, C3, wt4, T4, wtf, bf, out);
}